// Round 1
// baseline (652.151 us; speedup 1.0000x reference)
//
#include <hip/hip_runtime.h>
#include <math.h>

// Problem sizes (fixed by reference): B=4, T=2048, G=8, D=128, V=1024
#define BT 8192      // B*T tokens
#define NG 8
#define ND 128
#define NV 1024
#define VC 64        // codebook codes staged in LDS per chunk (32 KB)

// d_out layout (float32, concatenated in return order):
//   [0, 65536)              ids (B,T,G) as float (-1 for padded)
//   [65536, 65536+8388608)  quantized_st (B,T,G*D)
//   [+0,+1,+2]              kmeans_loss, commitment_loss, total_loss
#define OUT_IDS 0
#define OUT_Q   65536
#define OUT_L   (65536 + 8388608)

// ws layout (floats): c2[8192] | ids[65536] (int) | loss_partial[8192]
#define WSF_C2   0
#define WSF_IDS  8192
#define WSF_LOSS (8192 + 65536)

// ---------------------------------------------------------------------------
// Kernel 1: c2[v*8+g] = sum_d codebook[v][g][d]^2  (numpy-pairwise 8-acc order)
// ---------------------------------------------------------------------------
__global__ __launch_bounds__(256) void c2_kernel(const float* __restrict__ cb,
                                                 float* __restrict__ c2) {
    int idx = blockIdx.x * 256 + threadIdx.x;   // idx = v*8 + g, < 8192
    const float* row = cb + (size_t)idx * ND;
    float r[8];
#pragma unroll
    for (int j = 0; j < 8; ++j) r[j] = 0.0f;
#pragma unroll
    for (int k = 0; k < 16; ++k) {
#pragma unroll
        for (int j = 0; j < 8; ++j) {
            float c = row[k * 8 + j];
            float p = __fmul_rn(c, c);          // separate rounding (no fma)
            r[j] = __fadd_rn(r[j], p);
        }
    }
    float s = __fadd_rn(
        __fadd_rn(__fadd_rn(r[0], r[1]), __fadd_rn(r[2], r[3])),
        __fadd_rn(__fadd_rn(r[4], r[5]), __fadd_rn(r[6], r[7])));
    c2[idx] = s;
}

// ---------------------------------------------------------------------------
// Kernel 2: argmin over V for each (token, g).
// One thread per (token,g). x in VGPRs; codebook chunk in LDS, read as
// wave-uniform broadcasts. 4 codes interleaved, sequential-in-d accumulation.
// ---------------------------------------------------------------------------
__global__ __launch_bounds__(256, 1) void argmin_kernel(
    const float* __restrict__ x, const int* __restrict__ pad,
    const float* __restrict__ cb, const float* __restrict__ c2w,
    int* __restrict__ ws_ids, float* __restrict__ out_ids) {
    __shared__ float cs[VC * ND];   // 32 KB
    __shared__ float c2s[VC];

    const int tid = threadIdx.x;
    const int g = blockIdx.x & 7;
    const int n = (blockIdx.x >> 3) * 256 + tid;

    const float4* xr = (const float4*)(x + (size_t)n * (NG * ND) + g * ND);
    float4 xv[32];
#pragma unroll
    for (int i = 0; i < 32; ++i) xv[i] = xr[i];

    // x2: numpy-pairwise 8-accumulator over 128, mul+add (no contraction)
    float r[8];
#pragma unroll
    for (int j = 0; j < 8; ++j) r[j] = 0.0f;
#pragma unroll
    for (int i = 0; i < 32; ++i) {
        // element order d = i*4 + {0,1,2,3}; accumulator j = d & 7
        int j0 = (i * 4) & 7;
        r[j0 + 0] = __fadd_rn(r[j0 + 0], __fmul_rn(xv[i].x, xv[i].x));
        r[j0 + 1] = __fadd_rn(r[j0 + 1], __fmul_rn(xv[i].y, xv[i].y));
        r[j0 + 2] = __fadd_rn(r[j0 + 2], __fmul_rn(xv[i].z, xv[i].z));
        r[j0 + 3] = __fadd_rn(r[j0 + 3], __fmul_rn(xv[i].w, xv[i].w));
    }
    float x2 = __fadd_rn(
        __fadd_rn(__fadd_rn(r[0], r[1]), __fadd_rn(r[2], r[3])),
        __fadd_rn(__fadd_rn(r[4], r[5]), __fadd_rn(r[6], r[7])));

    float best = INFINITY;
    int bid = 0;

    for (int v0 = 0; v0 < NV; v0 += VC) {
        __syncthreads();
        // stage VC codes (rows of 128 floats) for group g
        for (int i = tid; i < VC * 32; i += 256) {
            int vc = i >> 5, d4 = i & 31;
            ((float4*)cs)[vc * 32 + d4] =
                ((const float4*)(cb + ((size_t)(v0 + vc) * NG + g) * ND))[d4];
        }
        if (tid < VC) c2s[tid] = c2w[(v0 + tid) * NG + g];
        __syncthreads();

#pragma unroll 1
        for (int vc = 0; vc < VC; vc += 4) {
            const float4* c0 = (const float4*)cs + (vc + 0) * 32;
            const float4* c1 = c0 + 32;
            const float4* c2p = c0 + 64;
            const float4* c3 = c0 + 96;
            float s0 = 0.f, s1 = 0.f, s2 = 0.f, s3 = 0.f;
#pragma unroll
            for (int i = 0; i < 32; ++i) {
                float4 a = xv[i];
                float4 q0 = c0[i], q1 = c1[i], q2 = c2p[i], q3 = c3[i];
                s0 = fmaf(a.x, q0.x, s0); s0 = fmaf(a.y, q0.y, s0);
                s0 = fmaf(a.z, q0.z, s0); s0 = fmaf(a.w, q0.w, s0);
                s1 = fmaf(a.x, q1.x, s1); s1 = fmaf(a.y, q1.y, s1);
                s1 = fmaf(a.z, q1.z, s1); s1 = fmaf(a.w, q1.w, s1);
                s2 = fmaf(a.x, q2.x, s2); s2 = fmaf(a.y, q2.y, s2);
                s2 = fmaf(a.z, q2.z, s2); s2 = fmaf(a.w, q2.w, s2);
                s3 = fmaf(a.x, q3.x, s3); s3 = fmaf(a.y, q3.y, s3);
                s3 = fmaf(a.z, q3.z, s3); s3 = fmaf(a.w, q3.w, s3);
            }
            // dist = (x2 - 2*xc) + c2, matching reference rounding order
            float d0 = __fadd_rn(__fsub_rn(x2, __fmul_rn(2.0f, s0)), c2s[vc + 0]);
            float d1 = __fadd_rn(__fsub_rn(x2, __fmul_rn(2.0f, s1)), c2s[vc + 1]);
            float d2 = __fadd_rn(__fsub_rn(x2, __fmul_rn(2.0f, s2)), c2s[vc + 2]);
            float d3 = __fadd_rn(__fsub_rn(x2, __fmul_rn(2.0f, s3)), c2s[vc + 3]);
            // strict < keeps first occurrence (ascending v) like jnp.argmin
            if (d0 < best) { best = d0; bid = v0 + vc + 0; }
            if (d1 < best) { best = d1; bid = v0 + vc + 1; }
            if (d2 < best) { best = d2; bid = v0 + vc + 2; }
            if (d3 < best) { best = d3; bid = v0 + vc + 3; }
        }
    }

    int p = pad[n];
    ws_ids[n * NG + g] = bid;
    out_ids[(size_t)n * NG + g] = p ? -1.0f : (float)bid;
}

// ---------------------------------------------------------------------------
// Kernel 3: gather quantized (masked), write quantized_st, per-token loss
// One block per token, 256 threads = 8 groups x 32 float4 lanes.
// ---------------------------------------------------------------------------
__global__ __launch_bounds__(256) void gather_kernel(
    const float* __restrict__ x, const int* __restrict__ pad,
    const float* __restrict__ cb, const int* __restrict__ ws_ids,
    float* __restrict__ out_q, float* __restrict__ ws_loss) {
    const int n = blockIdx.x;
    const int tid = threadIdx.x;
    const int g = tid >> 5;
    const int d4 = tid & 31;
    const int p = pad[n];

    float4 q = make_float4(0.f, 0.f, 0.f, 0.f);
    float s = 0.f;
    if (!p) {
        int id = ws_ids[n * NG + g];
        q = ((const float4*)(cb + ((size_t)id * NG + g) * ND))[d4];
        float4 a = ((const float4*)(x + (size_t)n * (NG * ND)))[tid];
        float e0 = q.x - a.x, e1 = q.y - a.y, e2 = q.z - a.z, e3 = q.w - a.w;
        s = e0 * e0 + e1 * e1 + e2 * e2 + e3 * e3;
    }
    ((float4*)(out_q + (size_t)n * (NG * ND)))[tid] = q;

    // deterministic block reduction of s
    for (int off = 32; off > 0; off >>= 1) s += __shfl_down(s, off);
    __shared__ float red[4];
    int w = tid >> 6, lane = tid & 63;
    if (lane == 0) red[w] = s;
    __syncthreads();
    if (tid == 0) ws_loss[n] = (red[0] + red[1]) + (red[2] + red[3]);
}

// ---------------------------------------------------------------------------
// Kernel 4: finalize losses (deterministic)
// ---------------------------------------------------------------------------
__global__ __launch_bounds__(256) void final_kernel(
    const int* __restrict__ pad, const float* __restrict__ ws_loss,
    float* __restrict__ out_l) {
    __shared__ float sr[256];
    __shared__ int mr[256];
    const int tid = threadIdx.x;
    float s = 0.f;
    int m = 0;
    for (int i = tid; i < BT; i += 256) {
        s += ws_loss[i];
        m += 1 - pad[i];
    }
    sr[tid] = s;
    mr[tid] = m;
    __syncthreads();
    for (int st = 128; st > 0; st >>= 1) {
        if (tid < st) { sr[tid] += sr[tid + st]; mr[tid] += mr[tid + st]; }
        __syncthreads();
    }
    if (tid == 0) {
        float k = sr[0] / (float)mr[0];
        out_l[0] = k;        // kmeans_loss
        out_l[1] = k;        // commitment_loss (bitwise identical sum)
        out_l[2] = k + k;    // total_loss
    }
}

// ---------------------------------------------------------------------------
extern "C" void kernel_launch(void* const* d_in, const int* in_sizes, int n_in,
                              void* d_out, int out_size, void* d_ws, size_t ws_size,
                              hipStream_t stream) {
    const float* x = (const float*)d_in[0];    // (4,2048,1024) f32
    const int* pad = (const int*)d_in[1];      // (4,2048) i32
    const float* cb = (const float*)d_in[2];   // (1024,8,128) f32
    float* out = (float*)d_out;
    float* ws = (float*)d_ws;

    float* ws_c2 = ws + WSF_C2;
    int* ws_ids = (int*)(ws + WSF_IDS);
    float* ws_loss = ws + WSF_LOSS;

    c2_kernel<<<NV * NG / 256, 256, 0, stream>>>(cb, ws_c2);
    argmin_kernel<<<(BT / 256) * NG, 256, 0, stream>>>(x, pad, cb, ws_c2, ws_ids,
                                                       out + OUT_IDS);
    gather_kernel<<<BT, 256, 0, stream>>>(x, pad, cb, ws_ids, out + OUT_Q, ws_loss);
    final_kernel<<<1, 256, 0, stream>>>(pad, ws_loss, out + OUT_L);
}

// Round 2
// 274.990 us; speedup vs baseline: 2.3715x; 2.3715x over previous
//
#include <hip/hip_runtime.h>
#include <math.h>

// Problem sizes (fixed by reference): B=4, T=2048, G=8, D=128, V=1024
#define BT 8192      // B*T tokens
#define NG 8
#define ND 128
#define NV 1024

// GEMM-argmin tiling
#define BM 128       // tokens per block
#define BN 128       // codes per block
#define BK 16        // k (d) chunk in LDS
#define LDP 132      // padded LDS row (floats) — kills staging write conflicts

// d_out layout (float32, concatenated in return order):
//   [0, 65536)              ids (B,T,G) as float (-1 for padded)
//   [65536, 65536+8388608)  quantized_st (B,T,G*D)
//   [+0,+1,+2]              kmeans_loss, commitment_loss, total_loss
#define OUT_IDS 0
#define OUT_Q   65536
#define OUT_L   (65536 + 8388608)

// ws layout (floats): c2[8192] | x2[65536] | ids[65536] (int) | loss[8192]
#define WSF_C2   0
#define WSF_X2   8192
#define WSF_IDS  (8192 + 65536)
#define WSF_LOSS (8192 + 65536 + 65536)

// ---------------------------------------------------------------------------
// Kernel 1: c2[v*8+g] = sum_d codebook[v][g][d]^2 (numpy-pairwise 8-acc order)
// ---------------------------------------------------------------------------
__global__ __launch_bounds__(256) void c2_kernel(const float* __restrict__ cb,
                                                 float* __restrict__ c2) {
    int idx = blockIdx.x * 256 + threadIdx.x;   // idx = v*8 + g, < 8192
    const float* row = cb + (size_t)idx * ND;
    float r[8];
#pragma unroll
    for (int j = 0; j < 8; ++j) r[j] = 0.0f;
#pragma unroll
    for (int k = 0; k < 16; ++k) {
#pragma unroll
        for (int j = 0; j < 8; ++j) {
            float c = row[k * 8 + j];
            float p = __fmul_rn(c, c);
            r[j] = __fadd_rn(r[j], p);
        }
    }
    c2[idx] = __fadd_rn(
        __fadd_rn(__fadd_rn(r[0], r[1]), __fadd_rn(r[2], r[3])),
        __fadd_rn(__fadd_rn(r[4], r[5]), __fadd_rn(r[6], r[7])));
}

// ---------------------------------------------------------------------------
// Kernel 2: x2[n*8+g] = sum_d x[n][g][d]^2  (identical op order to R1 kernel)
// ---------------------------------------------------------------------------
__global__ __launch_bounds__(256) void x2_kernel(const float* __restrict__ x,
                                                 float* __restrict__ x2o) {
    int idx = blockIdx.x * 256 + threadIdx.x;   // n*8+g
    const float4* xr = (const float4*)(x + (size_t)idx * ND);
    float r[8];
#pragma unroll
    for (int j = 0; j < 8; ++j) r[j] = 0.0f;
#pragma unroll
    for (int i = 0; i < 32; ++i) {
        float4 v = xr[i];
        int j0 = (i * 4) & 7;
        r[j0 + 0] = __fadd_rn(r[j0 + 0], __fmul_rn(v.x, v.x));
        r[j0 + 1] = __fadd_rn(r[j0 + 1], __fmul_rn(v.y, v.y));
        r[j0 + 2] = __fadd_rn(r[j0 + 2], __fmul_rn(v.z, v.z));
        r[j0 + 3] = __fadd_rn(r[j0 + 3], __fmul_rn(v.w, v.w));
    }
    x2o[idx] = __fadd_rn(
        __fadd_rn(__fadd_rn(r[0], r[1]), __fadd_rn(r[2], r[3])),
        __fadd_rn(__fadd_rn(r[4], r[5]), __fadd_rn(r[6], r[7])));
}

// ---------------------------------------------------------------------------
// Kernel 3: register-tiled GEMM + partial argmin.
// Block = (token-tile tm, code-tile bn, group g); 256 threads; 8x8 micro-tile.
// Per-wave 8x8 (rg,cg) tiling -> all ds_read_b128 at most 2-way bank aliased.
// Distances bitwise-identical to R1 kernel: sequential-d fmaf chain,
// (x2 - 2s) + c2 rounding, strict-< ascending-code argmin.
// ---------------------------------------------------------------------------
__global__ __launch_bounds__(256, 4) void argmin_gemm(
    const float* __restrict__ x, const float* __restrict__ cb,
    const float* __restrict__ c2w, const float* __restrict__ x2w,
    float2* __restrict__ part) {
    __shared__ float As[BK][LDP];
    __shared__ float Bs[BK][LDP];

    const int tid = threadIdx.x;
    const int b = blockIdx.x;
    const int bn = b & 7;           // code tile
    const int g = (b >> 3) & 7;     // group
    const int tm = b >> 6;          // token tile
    const int tok0 = tm * BM;
    const int vb0 = bn * BN;

    const int w = tid >> 6, lane = tid & 63;
    const int rg = ((w & 1) << 3) | (lane & 7);    // token group [0,16)
    const int cg = ((w >> 1) << 3) | (lane >> 3);  // code group  [0,16)

    float acc[8][8];
#pragma unroll
    for (int i = 0; i < 8; ++i)
#pragma unroll
        for (int j = 0; j < 8; ++j) acc[i][j] = 0.0f;

    // staging indices (i in [0,512): row = i>>2, d4 = i&3)
    const int i0 = tid, i1 = tid + 256;

#pragma unroll 1
    for (int kc = 0; kc < ND / BK; ++kc) {
        __syncthreads();
        {
            int r0 = i0 >> 2, d40 = i0 & 3;
            int r1 = i1 >> 2, d41 = i1 & 3;
            float4 va0 = *(const float4*)(x + ((size_t)(tok0 + r0) * NG + g) * ND + kc * BK + d40 * 4);
            float4 va1 = *(const float4*)(x + ((size_t)(tok0 + r1) * NG + g) * ND + kc * BK + d41 * 4);
            float4 vb0v = *(const float4*)(cb + ((size_t)(vb0 + r0) * NG + g) * ND + kc * BK + d40 * 4);
            float4 vb1v = *(const float4*)(cb + ((size_t)(vb0 + r1) * NG + g) * ND + kc * BK + d41 * 4);
            As[d40 * 4 + 0][r0] = va0.x; As[d40 * 4 + 1][r0] = va0.y;
            As[d40 * 4 + 2][r0] = va0.z; As[d40 * 4 + 3][r0] = va0.w;
            As[d41 * 4 + 0][r1] = va1.x; As[d41 * 4 + 1][r1] = va1.y;
            As[d41 * 4 + 2][r1] = va1.z; As[d41 * 4 + 3][r1] = va1.w;
            Bs[d40 * 4 + 0][r0] = vb0v.x; Bs[d40 * 4 + 1][r0] = vb0v.y;
            Bs[d40 * 4 + 2][r0] = vb0v.z; Bs[d40 * 4 + 3][r0] = vb0v.w;
            Bs[d41 * 4 + 0][r1] = vb1v.x; Bs[d41 * 4 + 1][r1] = vb1v.y;
            Bs[d41 * 4 + 2][r1] = vb1v.z; Bs[d41 * 4 + 3][r1] = vb1v.w;
        }
        __syncthreads();

#pragma unroll
        for (int k = 0; k < BK; ++k) {
            float4 a0 = *(const float4*)&As[k][rg * 8];
            float4 a1 = *(const float4*)&As[k][rg * 8 + 4];
            float4 b0 = *(const float4*)&Bs[k][cg * 8];
            float4 b1 = *(const float4*)&Bs[k][cg * 8 + 4];
            float a[8] = {a0.x, a0.y, a0.z, a0.w, a1.x, a1.y, a1.z, a1.w};
            float bb[8] = {b0.x, b0.y, b0.z, b0.w, b1.x, b1.y, b1.z, b1.w};
#pragma unroll
            for (int i = 0; i < 8; ++i)
#pragma unroll
                for (int j = 0; j < 8; ++j)
                    acc[i][j] = fmaf(a[i], bb[j], acc[i][j]);
        }
    }

    // epilogue: dist = (x2 - 2*s) + c2; per-token argmin over thread's 8 codes
    float c2r[8];
#pragma unroll
    for (int j = 0; j < 8; ++j)
        c2r[j] = c2w[(size_t)(vb0 + cg * 8 + j) * NG + g];

    __syncthreads();   // done reading As/Bs — reuse LDS for reduction
    float* redD = &As[0][0];                 // [cg][tok] 16x128
    int* redI = (int*)&Bs[0][0];

#pragma unroll
    for (int i = 0; i < 8; ++i) {
        int tok = rg * 8 + i;
        float x2v = x2w[(size_t)(tok0 + tok) * NG + g];
        float best = INFINITY;
        int bid = 0;
#pragma unroll
        for (int j = 0; j < 8; ++j) {
            float d = __fadd_rn(__fsub_rn(x2v, __fmul_rn(2.0f, acc[i][j])), c2r[j]);
            if (d < best) { best = d; bid = cg * 8 + j; }
        }
        redD[cg * 128 + tok] = best;
        redI[cg * 128 + tok] = bid;
    }
    __syncthreads();

    if (tid < BM) {
        int tok = tid;
        float best = INFINITY;
        int bid = 0;
#pragma unroll
        for (int c = 0; c < 16; ++c) {       // ascending code order
            float d = redD[c * 128 + tok];
            if (d < best) { best = d; bid = redI[c * 128 + tok]; }
        }
        float2 p;
        p.x = best;
        p.y = __int_as_float(vb0 + bid);
        part[((size_t)(tok0 + tok) * NG + g) * 8 + bn] = p;
    }
}

// ---------------------------------------------------------------------------
// Kernel 4: reduce partial argmins across the 8 code tiles (ascending)
// ---------------------------------------------------------------------------
__global__ __launch_bounds__(256) void reduce_kernel(
    const float2* __restrict__ part, const int* __restrict__ pad,
    int* __restrict__ ws_ids, float* __restrict__ out_ids) {
    int idx = blockIdx.x * 256 + threadIdx.x;  // n*8+g
    int n = idx >> 3;
    float best = INFINITY;
    int bid = 0;
#pragma unroll
    for (int bnn = 0; bnn < 8; ++bnn) {
        float2 p = part[(size_t)idx * 8 + bnn];
        if (p.x < best) { best = p.x; bid = __float_as_int(p.y); }
    }
    ws_ids[idx] = bid;
    out_ids[idx] = pad[n] ? -1.0f : (float)bid;
}

// ---------------------------------------------------------------------------
// Kernel 5: gather quantized (masked), write quantized_st, per-token loss
// ---------------------------------------------------------------------------
__global__ __launch_bounds__(256) void gather_kernel(
    const float* __restrict__ x, const int* __restrict__ pad,
    const float* __restrict__ cb, const int* __restrict__ ws_ids,
    float* __restrict__ out_q, float* __restrict__ ws_loss) {
    const int n = blockIdx.x;
    const int tid = threadIdx.x;
    const int g = tid >> 5;
    const int d4 = tid & 31;
    const int p = pad[n];

    float4 q = make_float4(0.f, 0.f, 0.f, 0.f);
    float s = 0.f;
    if (!p) {
        int id = ws_ids[n * NG + g];
        q = ((const float4*)(cb + ((size_t)id * NG + g) * ND))[d4];
        float4 a = ((const float4*)(x + (size_t)n * (NG * ND)))[tid];
        float e0 = q.x - a.x, e1 = q.y - a.y, e2 = q.z - a.z, e3 = q.w - a.w;
        s = e0 * e0 + e1 * e1 + e2 * e2 + e3 * e3;
    }
    ((float4*)(out_q + (size_t)n * (NG * ND)))[tid] = q;

    for (int off = 32; off > 0; off >>= 1) s += __shfl_down(s, off);
    __shared__ float red[4];
    int w = tid >> 6, lane = tid & 63;
    if (lane == 0) red[w] = s;
    __syncthreads();
    if (tid == 0) ws_loss[n] = (red[0] + red[1]) + (red[2] + red[3]);
}

// ---------------------------------------------------------------------------
// Kernel 6: finalize losses (deterministic)
// ---------------------------------------------------------------------------
__global__ __launch_bounds__(256) void final_kernel(
    const int* __restrict__ pad, const float* __restrict__ ws_loss,
    float* __restrict__ out_l) {
    __shared__ float sr[256];
    __shared__ int mr[256];
    const int tid = threadIdx.x;
    float s = 0.f;
    int m = 0;
    for (int i = tid; i < BT; i += 256) {
        s += ws_loss[i];
        m += 1 - pad[i];
    }
    sr[tid] = s;
    mr[tid] = m;
    __syncthreads();
    for (int st = 128; st > 0; st >>= 1) {
        if (tid < st) { sr[tid] += sr[tid + st]; mr[tid] += mr[tid + st]; }
        __syncthreads();
    }
    if (tid == 0) {
        float k = sr[0] / (float)mr[0];
        out_l[0] = k;
        out_l[1] = k;
        out_l[2] = k + k;
    }
}

// ---------------------------------------------------------------------------
extern "C" void kernel_launch(void* const* d_in, const int* in_sizes, int n_in,
                              void* d_out, int out_size, void* d_ws, size_t ws_size,
                              hipStream_t stream) {
    const float* x = (const float*)d_in[0];    // (4,2048,1024) f32
    const int* pad = (const int*)d_in[1];      // (4,2048) i32
    const float* cb = (const float*)d_in[2];   // (1024,8,128) f32
    float* out = (float*)d_out;
    float* ws = (float*)d_ws;

    float* ws_c2 = ws + WSF_C2;
    float* ws_x2 = ws + WSF_X2;
    int* ws_ids = (int*)(ws + WSF_IDS);
    float* ws_loss = ws + WSF_LOSS;

    // partial argmins parked in the quantized-output region (overwritten by
    // gather_kernel afterwards): 65536 * 8 * sizeof(float2) = 4 MB << 33 MB
    float2* part = (float2*)(out + OUT_Q);

    c2_kernel<<<NV * NG / 256, 256, 0, stream>>>(cb, ws_c2);
    x2_kernel<<<BT * NG / 256, 256, 0, stream>>>(x, ws_x2);
    argmin_gemm<<<(BT / BM) * (NV / BN) * NG, 256, 0, stream>>>(x, cb, ws_c2,
                                                                ws_x2, part);
    reduce_kernel<<<BT * NG / 256, 256, 0, stream>>>(part, pad, ws_ids,
                                                     out + OUT_IDS);
    gather_kernel<<<BT, 256, 0, stream>>>(x, pad, cb, ws_ids, out + OUT_Q, ws_loss);
    final_kernel<<<1, 256, 0, stream>>>(pad, ws_loss, out + OUT_L);
}